// Round 10
// baseline (75059.058 us; speedup 1.0000x reference)
//
#include <hip/hip_runtime.h>

#define BB 128
#define TT 512
#define DD 256
#define HH 512

__device__ __forceinline__ float sig_(float x) { return 1.0f / (1.0f + __expf(-x)); }

#define FMA4(ACC, AV, WV)                     \
  do {                                        \
    ACC[0] = fmaf((AV), (WV).x, ACC[0]);      \
    ACC[1] = fmaf((AV), (WV).y, ACC[1]);      \
    ACC[2] = fmaf((AV), (WV).z, ACC[2]);      \
    ACC[3] = fmaf((AV), (WV).w, ACC[3]);      \
  } while (0)

// Persistent c-state across per-phase launches. Block-private (each thread
// owns its 4 elements), so plain loads/stores + kernel-boundary ordering
// are sufficient. 512 KB device-global (zero ws growth). Re-initialized by
// the first==true branch every sequence (idempotent across harness re-runs).
__device__ float g_c[2 * BB * HH];

// ---------------- projection GEMM: xp = x @ proj_w.T + proj_b ----------------
// (unchanged, known-good)
__global__ __launch_bounds__(256) void proj_kernel(const float* __restrict__ x,
                                                   const float* __restrict__ pw,
                                                   const float* __restrict__ pb,
                                                   float* __restrict__ xp) {
  __shared__ float At[64 * 68];
  __shared__ float Bt[64 * 68];
  const int bm = blockIdx.x >> 2;
  const int bn = blockIdx.x & 3;
  const int tid = threadIdx.x;
  const int rg = tid >> 4;
  const int cgi = tid & 15;
  const int m0 = bm * 64, n0 = bn * 64;
  float acc[4][4] = {};
  for (int kt = 0; kt < 4; ++kt) {
    const int k0 = kt * 64;
    {
      const int r = tid >> 2, q = tid & 3;
      const float4* src = (const float4*)(x + (size_t)(m0 + r) * DD + k0 + q * 16);
      float4* dst = (float4*)&At[r * 68 + q * 16];
#pragma unroll
      for (int j = 0; j < 4; ++j) dst[j] = src[j];
    }
    {
      const int n = tid & 63, kg = tid >> 6;
      const float4* src = (const float4*)(pw + (size_t)(n0 + n) * DD + k0 + kg * 16);
#pragma unroll
      for (int j = 0; j < 4; ++j) {
        float4 v = src[j];
        const int kk = kg * 16 + j * 4;
        Bt[(kk + 0) * 68 + n] = v.x;
        Bt[(kk + 1) * 68 + n] = v.y;
        Bt[(kk + 2) * 68 + n] = v.z;
        Bt[(kk + 3) * 68 + n] = v.w;
      }
    }
    __syncthreads();
#pragma unroll
    for (int k4 = 0; k4 < 64; k4 += 4) {
      float4 a[4], b[4];
#pragma unroll
      for (int j = 0; j < 4; ++j) a[j] = *(const float4*)&At[(rg * 4 + j) * 68 + k4];
#pragma unroll
      for (int j = 0; j < 4; ++j) b[j] = *(const float4*)&Bt[(k4 + j) * 68 + cgi * 4];
#pragma unroll
      for (int jr = 0; jr < 4; ++jr) {
        FMA4(acc[jr], a[jr].x, b[0]);
        FMA4(acc[jr], a[jr].y, b[1]);
        FMA4(acc[jr], a[jr].z, b[2]);
        FMA4(acc[jr], a[jr].w, b[3]);
      }
    }
    __syncthreads();
  }
  const float4 bias = *(const float4*)&pb[n0 + cgi * 4];
#pragma unroll
  for (int jr = 0; jr < 4; ++jr) {
    float4 o;
    o.x = acc[jr][0] + bias.x;
    o.y = acc[jr][1] + bias.y;
    o.z = acc[jr][2] + bias.z;
    o.w = acc[jr][3] + bias.w;
    *(float4*)&xp[(size_t)(m0 + rg * 4 + jr) * DD + n0 + cgi * 4] = o;
  }
}

// ---------------- per-phase 2-layer LSTM step -------------------------------
// ONE LAUNCH PER PHASE (513 total). Kernel boundaries = grid barrier +
// coherence (proven r8). Grid 256 blocks x 128 THREADS, 1 block/CU.
// Blocks 0..127: layer0 step p; 128..255: layer1 step p-1.
// Register blocking R4xC4: thread = 4 rows x 1 cell x 4 gates (16 acc).
// 64 FMA per 8 ds_read_b128 (was 32 per 6) -> per-CU LDS reads 6144->4096.
// Accumulation order per output stays strictly k-ascending (bit-exact).

// --- A-tile reg staging: 16 x float4 per thread (128 rows x 64 k per tile) --
__device__ __forceinline__ void load_plain(float4 (&R)[16], const float* base,
                                           size_t rs, int trb, int gq) {
#pragma unroll
  for (int j = 0; j < 16; ++j)
    R[j] = *(const float4*)(base + (size_t)(j * 8 + trb) * rs + (gq << 2));
}

// LDS A layout: row r, granule g stored at r*64 + (g ^ ((r>>2)&7))*4.
// Key uses (r>>2): a thread's 4 consecutive rows share one key (single
// read offset); read-side = 16 unique 16B slots, 2 rowg per slot = 2-way.
__device__ __forceinline__ void write_tile(float* Abuf, const float4 (&R)[16],
                                           int trb, int gq) {
#pragma unroll
  for (int j = 0; j < 16; ++j) {
    const int row = j * 8 + trb;
    const int wp = gq ^ ((row >> 2) & 7);
    *(float4*)&Abuf[row * 64 + (wp << 2)] = R[j];
  }
}

__device__ __forceinline__ void compute_tile(float acc[4][4],
                                             const float* Abuf, const float* Wl,
                                             int kt, int rowg, int cell) {
  const float* Wt = Wl + (kt << 10) + (cell << 2);
  const float* Ar = Abuf + rowg * 256;   // 4 rows x 64 floats
  const int key = rowg & 7;              // (row>>2)&7 for rows 4*rowg..+3
#pragma unroll
  for (int k4 = 0; k4 < 64; k4 += 4) {
    const int off = (((k4 >> 2) ^ key) << 2);
    float4 a[4];
#pragma unroll
    for (int i = 0; i < 4; ++i) a[i] = *(const float4*)(Ar + i * 64 + off);
    const float* wp = Wt + (k4 << 4);
    const float4 w0 = *(const float4*)(wp + 0);
    const float4 w1 = *(const float4*)(wp + 16);
    const float4 w2 = *(const float4*)(wp + 32);
    const float4 w3 = *(const float4*)(wp + 48);
#pragma unroll
    for (int i = 0; i < 4; ++i) {
      FMA4(acc[i], a[i].x, w0);
      FMA4(acc[i], a[i].y, w1);
      FMA4(acc[i], a[i].z, w2);
      FMA4(acc[i], a[i].w, w3);
    }
  }
}

__global__ __launch_bounds__(128, 1) void lstm_phase(
    const float* __restrict__ xp,
    const float* __restrict__ wx0, const float* __restrict__ bx0,
    const float* __restrict__ wh0, const float* __restrict__ bh0,
    const float* __restrict__ wx1, const float* __restrict__ bx1,
    const float* __restrict__ wh1, const float* __restrict__ bh1,
    float* __restrict__ h0buf, float* __restrict__ h1buf, int p) {
  __shared__ float Wl[16384];    // W slice [k][16 cols], pitch 16 (64 KB)
  __shared__ float Ab[2][8192];  // A tiles, swizzled (2 x 32 KB)

  const int bidx = blockIdx.x;
  const int role = bidx >> 7;  // 0: layer0, 1: layer1
  const bool active = role ? (p >= 1) : (p < TT);
  if (!active) return;

  const int bj = bidx & 127;   // cell-slice: cells bj*4 .. bj*4+3
  const int tid = threadIdx.x;
  const int cell = tid & 3;
  const int rowg = tid >> 2;   // 0..31 -> rows rowg*4 .. +3
  const int trb = tid >> 4;    // 0..7 staging row base
  const int gq = tid & 15;     // staging granule
  const int cell_g = bj * 4 + cell;

  const float* __restrict__ wx = role ? wx1 : wx0;
  const float* __restrict__ wh = role ? wh1 : wh0;
  const float* __restrict__ bxv = role ? bx1 : bx0;
  const float* __restrict__ bhv = role ? bh1 : bh0;
  const int KX = role ? HH : DD;   // K of the "x" operand
  const int nt = (KX + HH) >> 6;   // 12 (L0) or 16 (L1) K-tiles

  // ---- stage weight slice into LDS: Wl[k*16 + (lc*4+g)] ----
  {
    const int col = tid & 15, part = tid >> 4;  // 8 parts
    const int lc = col >> 2, g = col & 3;
    const int grow = g * HH + bj * 4 + lc;  // global gate row 0..2047
    const int span = (KX + HH) >> 3;        // 96 or 128 k per thread
    const int k0 = part * span;
    for (int k = k0; k < k0 + span; k += 4) {
      float4 v;
      if (k < KX) v = *(const float4*)(wx + (size_t)grow * KX + k);
      else        v = *(const float4*)(wh + (size_t)grow * HH + (k - KX));
      Wl[(k + 0) * 16 + col] = v.x;
      Wl[(k + 1) * 16 + col] = v.y;
      Wl[(k + 2) * 16 + col] = v.z;
      Wl[(k + 3) * 16 + col] = v.w;
    }
  }

  float bg[4];
#pragma unroll
  for (int g = 0; g < 4; ++g)
    bg[g] = bxv[(size_t)g * HH + cell_g] + bhv[(size_t)g * HH + cell_g];

  const int t = role ? (p - 1) : p;
  const int rd = (p + 1) & 1;  // buffer written during phase p-1
  const int wr = p & 1;
  const float* __restrict__ h0rd = h0buf + (size_t)rd * BB * HH;
  const float* __restrict__ h1rd = h1buf + (size_t)rd * BB * HH;
  float* __restrict__ hout = (role ? h1buf : h0buf) + (size_t)wr * BB * HH;

  // c-state: first step of this layer starts from 0 (re-inits every sequence)
  const bool first = role ? (p == 1) : (p == 0);
  float cst[4];
#pragma unroll
  for (int i = 0; i < 4; ++i)
    cst[i] = first ? 0.0f
                   : g_c[((size_t)role * BB + rowg * 4 + i) * HH + cell_g];

  float acc[4][4] = {};

  auto srcload = [&](float4(&R)[16], int kt) {
    if (role == 0) {
      if (kt < 4)
        load_plain(R, xp + (size_t)t * DD + kt * 64, (size_t)TT * DD, trb, gq);
      else
        load_plain(R, h0rd + (kt - 4) * 64, (size_t)HH, trb, gq);
    } else {
      if (kt < 8) load_plain(R, h0rd + kt * 64, (size_t)HH, trb, gq);
      else        load_plain(R, h1rd + (kt - 8) * 64, (size_t)HH, trb, gq);
    }
  };

  float4 ra[16], rb4[16];
  srcload(ra, 0);
  __syncthreads();  // Wl staged
#pragma unroll 1
  for (int kt = 0; kt < nt; kt += 2) {  // nt is even (12 or 16)
    srcload(rb4, kt + 1);
    write_tile(Ab[0], ra, trb, gq);
    __syncthreads();
    compute_tile(acc, Ab[0], Wl, kt, rowg, cell);
    if (kt + 2 < nt) srcload(ra, kt + 2);
    __syncthreads();                 // buf0 readers done
    write_tile(Ab[1], rb4, trb, gq);
    __syncthreads();
    compute_tile(acc, Ab[1], Wl, kt + 1, rowg, cell);
    __syncthreads();                 // buf1 readers done (before next write)
  }

  // ---- cell update + h store (plain; kernel boundary publishes) ----
#pragma unroll
  for (int i = 0; i < 4; ++i) {
    const float iv = acc[i][0] + bg[0];
    const float fv = acc[i][1] + bg[1];
    const float gv = acc[i][2] + bg[2];
    const float ov = acc[i][3] + bg[3];
    const float cn = sig_(fv) * cst[i] + sig_(iv) * tanhf(gv);
    g_c[((size_t)role * BB + rowg * 4 + i) * HH + cell_g] = cn;
    hout[(size_t)(rowg * 4 + i) * HH + cell_g] = sig_(ov) * tanhf(cn);
  }
}

// ---------------- head: out = relu(h1 @ fc1.T + b1) @ fc2.T + b2 ------------
__global__ __launch_bounds__(256) void head_kernel(const float* __restrict__ h1,
                                                   const float* __restrict__ fc1w,
                                                   const float* __restrict__ fc1b,
                                                   const float* __restrict__ fc2w,
                                                   const float* __restrict__ fc2b,
                                                   float* __restrict__ out) {
  __shared__ float part[256];
  __shared__ float hid[32];
  const int r = blockIdx.x;
  const int tid = threadIdx.x;
  const int c = tid & 31, pt = tid >> 5;
  const float4* ha = (const float4*)(h1 + (size_t)r * HH + pt * 64);
  const float4* wa = (const float4*)(fc1w + (size_t)c * HH + pt * 64);
  float s = 0.f;
#pragma unroll
  for (int j = 0; j < 16; ++j) {
    float4 av = ha[j], wv = wa[j];
    s = fmaf(av.x, wv.x, s);
    s = fmaf(av.y, wv.y, s);
    s = fmaf(av.z, wv.z, s);
    s = fmaf(av.w, wv.w, s);
  }
  part[tid] = s;
  __syncthreads();
  if (tid < 32) {
    float v = fc1b[tid];
#pragma unroll
    for (int q = 0; q < 8; ++q) v += part[q * 32 + tid];
    hid[tid] = fmaxf(v, 0.f);
  }
  __syncthreads();
  if (tid == 0) {
    float v = fc2b[0];
    for (int cc = 0; cc < 32; ++cc) v = fmaf(hid[cc], fc2w[cc], v);
    out[r] = v;
  }
}

extern "C" void kernel_launch(void* const* d_in, const int* in_sizes, int n_in,
                              void* d_out, int out_size, void* d_ws, size_t ws_size,
                              hipStream_t stream) {
  const float* x    = (const float*)d_in[0];
  const float* pw   = (const float*)d_in[1];
  const float* pb   = (const float*)d_in[2];
  const float* wx0  = (const float*)d_in[3];
  const float* bx0  = (const float*)d_in[4];
  const float* wh0  = (const float*)d_in[5];
  const float* bh0  = (const float*)d_in[6];
  const float* wx1  = (const float*)d_in[7];
  const float* bx1  = (const float*)d_in[8];
  const float* wh1  = (const float*)d_in[9];
  const float* bh1  = (const float*)d_in[10];
  const float* fc1w = (const float*)d_in[11];
  const float* fc1b = (const float*)d_in[12];
  const float* fc2w = (const float*)d_in[13];
  const float* fc2b = (const float*)d_in[14];
  float* out = (float*)d_out;

  // ws layout (floats): xp [B*T*D] | h0buf [2*B*H] | h1buf [2*B*H]
  // — EXACTLY the round-0/1/8 proven footprint, nothing appended.
  float* xp = (float*)d_ws;
  float* h0buf = xp + (size_t)BB * TT * DD;
  float* h1buf = h0buf + 2 * BB * HH;

  // zero initial h state (both buffers, both slots; 1 MB, stream-ordered)
  hipMemsetAsync(h0buf, 0, (size_t)4 * BB * HH * sizeof(float), stream);

  proj_kernel<<<dim3(4096), dim3(256), 0, stream>>>(x, pw, pb, xp);

  // 513 per-phase launches: kernel boundaries = grid barrier + coherence.
  for (int p = 0; p <= TT; ++p) {
    lstm_phase<<<dim3(256), dim3(128), 0, stream>>>(
        xp, wx0, bx0, wh0, bh0, wx1, bx1, wh1, bh1, h0buf, h1buf, p);
  }

  // final h1 lives in buffer index (512 & 1) == 0
  head_kernel<<<dim3(BB), dim3(256), 0, stream>>>(h1buf, fc1w, fc1b, fc2w, fc2b, out);
}